// Round 9
// baseline (4226.780 us; speedup 1.0000x reference)
//
#include <hip/hip_runtime.h>
#include <math.h>

// ---------------------------------------------------------------------------
// Stacked vanilla RNN (2 layers), SEQ=128 B=64 E=512 H=1024 V=10000.
// Persistent 256-WG mega-kernel:
//   WGs 0..191  : r2-proven fused recurrence (roles L0/P/L1, global barrier,
//                 130 stages @ ~10.3us), weights self-staged from f32.
//   WGs 192..255: XW role. Phase A: incremental XP0 (3-pass, per-slot,
//                 publishes high-water counter consumed by L0). Phase B:
//                 streaming logits GEMM — computes slot s's 64xV logit rows
//                 as soon as barrier flags show h1[s] is published.
// Serial prep: gather_x, hid_cast, W_out transpose only.
// r9 fix vs r8: phase-A XP0 store used XP0 + t*BH_ + row*H_ with row already
// global (t*64+b) — t double-counted, writes ran past XP0 into Pbuf/H0hi.
// Now stores at XP0 + row*H_ (identical layout to L0's read).
// ---------------------------------------------------------------------------

typedef unsigned short u16;
typedef unsigned int u32;
typedef unsigned long long u64;
typedef __bf16 bf16x8 __attribute__((ext_vector_type(8)));
typedef float  f32x4  __attribute__((ext_vector_type(4)));
typedef u32 u32x4 __attribute__((ext_vector_type(4)));
typedef u16 u16x8 __attribute__((ext_vector_type(8)));

#define SEQ_ 128
#define B_   64
#define E_   512
#define H_   1024
#define V_   10000
#define VP_  10112
#define ROWS_ (SEQ_*B_)      // 8192
#define BH_  (B_*H_)         // 65536
#define LOGITS_ 81920000     // SEQ*B*V

__device__ __forceinline__ u16 f2bf(float f) {          // RNE f32 -> bf16
  unsigned u = __builtin_bit_cast(unsigned, f);
  u += 0x7fffu + ((u >> 16) & 1u);
  return (u16)(u >> 16);
}
__device__ __forceinline__ float bf2f(u16 h) {
  unsigned u = ((unsigned)h) << 16;
  return __builtin_bit_cast(float, u);
}
__device__ __forceinline__ void st64(void* p, u64 v) {   // agent write-through
  __hip_atomic_store((u64*)p, v, __ATOMIC_RELAXED, __HIP_MEMORY_SCOPE_AGENT);
}
__device__ __forceinline__ u64 pk64(float a, float b) {
  return (u64)__builtin_bit_cast(unsigned, a) |
         ((u64)__builtin_bit_cast(unsigned, b) << 32);
}
__device__ __forceinline__ float tanh_fast(float x) {
  float e = __expf(2.0f * x);
  return 1.0f - 2.0f * __builtin_amdgcn_rcpf(e + 1.0f);
}

// --------------------------- prep kernels ----------------------------------

// in: f32 [K][N] row-major -> out: bf16 [NP][K] (transposed). For W_out only.
__global__ __launch_bounds__(256)
void transpose_bf16(const float* __restrict__ in, u16* __restrict__ outHi,
                    int K, int N)
{
  __shared__ float tile[32][33];
  const int n0 = blockIdx.x * 32, k0 = blockIdx.y * 32;
  const int x = threadIdx.x & 31;
  const int y = threadIdx.x >> 5;
#pragma unroll
  for (int i = 0; i < 4; ++i) {
    const int r = y * 4 + i;
    const int n = n0 + x;
    tile[r][x] = (n < N) ? in[(size_t)(k0 + r) * N + n] : 0.f;
  }
  __syncthreads();
#pragma unroll
  for (int i = 0; i < 4; ++i) {
    const int r = y * 4 + i;
    outHi[(size_t)(n0 + r) * K + k0 + x] = f2bf(tile[x][r]);
  }
}

__global__ __launch_bounds__(256)
void gather_x(const int* __restrict__ toks, const float* __restrict__ emb,
              u16* __restrict__ XBhi, u16* __restrict__ XBlo)
{
  const int tid = blockIdx.x * 256 + threadIdx.x;
  const int row = tid >> 6;
  const int c8 = (tid & 63) * 8;
  const int tok = toks[row];
  const float* e = emb + (size_t)tok * E_ + c8;
  u16x8 hv, lv;
#pragma unroll
  for (int j = 0; j < 8; ++j) {
    float f = e[j] * 22.627416997969522f;            // sqrt(512)
    u16 hb = f2bf(f);
    hv[j] = hb;
    lv[j] = f2bf(f - bf2f(hb));
  }
  *(u16x8*)(XBhi + (size_t)row * E_ + c8) = hv;
  *(u16x8*)(XBlo + (size_t)row * E_ + c8) = lv;
}

__global__ __launch_bounds__(256)
void hid_cast(const float* __restrict__ h, u16* H0hi, u16* H0lo, u16* H1hi, u16* H1lo)
{
  const int tid = blockIdx.x * 256 + threadIdx.x;
  float v0 = h[tid], v1 = h[BH_ + tid];
  u16 a = f2bf(v0); H0hi[tid] = a; H0lo[tid] = f2bf(v0 - bf2f(a));
  u16 b = f2bf(v1); H1hi[tid] = b; H1lo[tid] = f2bf(v1 - bf2f(b));
}

// --------------------------- barrier (r2-proven) ----------------------------
// 192 arrivals; every recurrence WG's wave0 scans all 192 flags.
__device__ __forceinline__ void gbar(unsigned* flags, unsigned my)
{
  asm volatile("s_waitcnt vmcnt(0)" ::: "memory");
  __syncthreads();
  if (threadIdx.x == 0)
    __hip_atomic_store(flags + blockIdx.x * 16u, my, __ATOMIC_RELAXED,
                       __HIP_MEMORY_SCOPE_AGENT);
  if (threadIdx.x < 64) {
    const int l = threadIdx.x;
    bool ok0 = false, ok1 = false, ok2 = false;
    for (;;) {
      if (!ok0) ok0 = __hip_atomic_load(flags + l * 16,         __ATOMIC_RELAXED, __HIP_MEMORY_SCOPE_AGENT) >= my;
      if (!ok1) ok1 = __hip_atomic_load(flags + (l + 64) * 16,  __ATOMIC_RELAXED, __HIP_MEMORY_SCOPE_AGENT) >= my;
      if (!ok2) ok2 = __hip_atomic_load(flags + (l + 128) * 16, __ATOMIC_RELAXED, __HIP_MEMORY_SCOPE_AGENT) >= my;
      if (__all(ok0 && ok1 && ok2)) break;
      __builtin_amdgcn_s_sleep(2);
    }
  }
  __syncthreads();
}
// W-role read-only wait: all 192 flags >= target (no arrival).
__device__ __forceinline__ void wait_flags(const unsigned* flags, unsigned tgt)
{
  if (threadIdx.x < 64) {
    const int l = threadIdx.x;
    bool ok0 = false, ok1 = false, ok2 = false;
    for (;;) {
      if (!ok0) ok0 = __hip_atomic_load(flags + l * 16,         __ATOMIC_RELAXED, __HIP_MEMORY_SCOPE_AGENT) >= tgt;
      if (!ok1) ok1 = __hip_atomic_load(flags + (l + 64) * 16,  __ATOMIC_RELAXED, __HIP_MEMORY_SCOPE_AGENT) >= tgt;
      if (!ok2) ok2 = __hip_atomic_load(flags + (l + 128) * 16, __ATOMIC_RELAXED, __HIP_MEMORY_SCOPE_AGENT) >= tgt;
      if (__all(ok0 && ok1 && ok2)) break;
      __builtin_amdgcn_s_sleep(4);
    }
  }
  __syncthreads();
}

// --------------------------- recurrence GEMM core ---------------------------
// 96 MFMAs: acc += Ahi*Bhi + Ahi*Blo + Alo*Bhi over K=1024, 3 acc chains.
__device__ __forceinline__ f32x4 gemm96(const u16* __restrict__ Ahi,
                                        const u16* __restrict__ Alo,
                                        const u16* bsp, int xorv, int lk8,
                                        size_t aoff, f32x4 acc0)
{
  f32x4 acc1 = {0.f, 0.f, 0.f, 0.f};
  f32x4 acc2 = {0.f, 0.f, 0.f, 0.f};
#pragma unroll
  for (int kc = 0; kc < 32; ++kc) {
    bf16x8 ah = *(const bf16x8*)(Ahi + aoff + kc * 32);
    bf16x8 al = *(const bf16x8*)(Alo + aoff + kc * 32);
    bf16x8 bh = *(const bf16x8*)(bsp + ((kc * 32 + lk8) ^ xorv));
    bf16x8 bl = *(const bf16x8*)(bsp + 32768 + ((kc * 32 + lk8) ^ xorv));
    acc0 = __builtin_amdgcn_mfma_f32_16x16x32_bf16(bh, ah, acc0, 0, 0, 0);
    acc1 = __builtin_amdgcn_mfma_f32_16x16x32_bf16(bl, ah, acc1, 0, 0, 0);
    acc2 = __builtin_amdgcn_mfma_f32_16x16x32_bf16(bh, al, acc2, 0, 0, 0);
  }
  return acc0 + acc1 + acc2;
}

// --------------------------- mega kernel ------------------------------------
__global__ __launch_bounds__(256, 1)
void rnn_mega(const float* __restrict__ Wh,    // (2,H,H) f32, layer-major
              const float* __restrict__ Wx1f,  // (H,H)  f32
              const float* __restrict__ Wx0f,  // (E,H)  f32
              const u16*   __restrict__ WoutT, // (VP,H) bf16 [n][k]
              const u16*   __restrict__ XBhi, const u16* __restrict__ XBlo,
              const float* __restrict__ bh,    // (2,H)
              const float* __restrict__ bout,  // (V)
              float* __restrict__ XP0, float* __restrict__ Pbuf,
              u16* __restrict__ H0hi, u16* __restrict__ H0lo,
              u16* __restrict__ H1hi, u16* __restrict__ H1lo,
              float* __restrict__ out,
              float* __restrict__ final0, float* __restrict__ final1,
              unsigned* __restrict__ flags, unsigned* __restrict__ xpcnt,
              unsigned* __restrict__ xphw)
{
  __shared__ u16 bsm[2 * 32 * 1024];   // 128 KB, role-dependent layout

  const int wg   = blockIdx.x;
  const int tid  = threadIdx.x;
  const int wv   = tid >> 6, lane = tid & 63;
  const int lb   = lane & 15;
  const int lk8  = (lane >> 4) * 8;

  if (wg < 192) {
    // ===================== recurrence roles (r2 structure) =================
    const int role = wg >> 6;           // 0=L0, 1=P, 2=L1
    const int idx  = wg & 63;
    const int bg   = idx >> 5, cg = idx & 31;

    // self-stage 32-col weight strip (hi+lo) from original f32 [k][n]
    const float* Wsrc = (role == 0) ? Wh : (role == 1) ? Wx1f : (Wh + H_ * H_);
    for (int j = tid; j < 32768; j += 256) {
      const int k = j >> 5, c = j & 31;
      const float v = Wsrc[(size_t)k * H_ + cg * 32 + c];
      const u16 hb = f2bf(v);
      const int ks = ((k & ~7) ^ ((c & 7) << 3)) | (k & 7);
      bsm[c * 1024 + ks] = hb;
      bsm[32768 + c * 1024 + ks] = f2bf(v - bf2f(hb));
    }
    __syncthreads();

    const int wbg = wv >> 1, wcg = wv & 1;
    const int batch = bg * 32 + wbg * 16 + lb;
    const int c0    = cg * 32 + wcg * 16 + (lk8 >> 1);
    const int colL  = wcg * 16 + lb;
    const int xorv  = (colL & 7) << 3;
    const u16* bsp  = bsm + colL * 1024;
    const size_t aoff = (size_t)batch * H_ + lk8;
    const size_t boff = (size_t)batch * H_ + c0;
    const f32x4 binit = *(const f32x4*)(bh + H_ + c0);   // b1 (used by P)

    unsigned xph = 0;                                    // L0: cached high-water
    for (int i = 0; i < 130; ++i) {
      if (role == 0) {
        if (i < 128) {
          const int t = i;
          if (tid < 64) {                                // gate on XP0[t]
            while (xph <= (unsigned)t) {
              xph = __hip_atomic_load(xphw, __ATOMIC_RELAXED, __HIP_MEMORY_SCOPE_AGENT);
              if (xph <= (unsigned)t) __builtin_amdgcn_s_sleep(2);
            }
          }
          __syncthreads();
          f32x4 init = *(const f32x4*)(XP0 + (size_t)t * BH_ + boff);
          f32x4 acc = gemm96(H0hi + (size_t)t * BH_, H0lo + (size_t)t * BH_,
                             bsp, xorv, lk8, aoff, init);
          u64 whi = 0, wlo = 0; float hv[4];
#pragma unroll
          for (int r = 0; r < 4; ++r) {
            float v = tanh_fast(acc[r]);
            u16 hb = f2bf(v);
            whi |= (u64)hb << (16 * r);
            wlo |= (u64)f2bf(v - bf2f(hb)) << (16 * r);
            hv[r] = v;
          }
          st64(H0hi + (size_t)(t + 1) * BH_ + boff, whi);
          st64(H0lo + (size_t)(t + 1) * BH_ + boff, wlo);
          if (t == SEQ_ - 1) {
            st64(final0 + boff,     pk64(hv[0], hv[1]));
            st64(final0 + boff + 2, pk64(hv[2], hv[3]));
          }
        }
      } else if (role == 1) {
        if (i >= 1 && i < 129) {
          f32x4 acc = gemm96(H0hi + (size_t)i * BH_, H0lo + (size_t)i * BH_,
                             bsp, xorv, lk8, aoff, binit);
          float* op = Pbuf + (size_t)(i - 1) * BH_ + boff;
          st64(op,     pk64(acc[0], acc[1]));
          st64(op + 2, pk64(acc[2], acc[3]));
        }
      } else {
        if (i >= 2) {
          const int t = i - 2;
          f32x4 init = *(const f32x4*)(Pbuf + (size_t)t * BH_ + boff);
          f32x4 acc = gemm96(H1hi + (size_t)t * BH_, H1lo + (size_t)t * BH_,
                             bsp, xorv, lk8, aoff, init);
          u64 whi = 0, wlo = 0; float hv[4];
#pragma unroll
          for (int r = 0; r < 4; ++r) {
            float v = tanh_fast(acc[r]);
            u16 hb = f2bf(v);
            whi |= (u64)hb << (16 * r);
            wlo |= (u64)f2bf(v - bf2f(hb)) << (16 * r);
            hv[r] = v;
          }
          st64(H1hi + (size_t)(t + 1) * BH_ + boff, whi);
          st64(H1lo + (size_t)(t + 1) * BH_ + boff, wlo);
          if (t == SEQ_ - 1) {
            st64(final1 + boff,     pk64(hv[0], hv[1]));
            st64(final1 + boff + 2, pk64(hv[2], hv[3]));
          }
        }
      }
      gbar(flags, (unsigned)(i + 1));
    }
  } else {
    // ============================ XW role ==================================
    const int u = wg - 192;                              // 0..63

    // ---- Phase A: incremental XP0 (16-col strip, K=512, 3-pass) ----
    for (int j = tid; j < 8192; j += 256) {              // stage Wx0 strip
      const int k = j >> 4, c = j & 15;
      const float v = Wx0f[(size_t)k * H_ + u * 16 + c];
      const u16 hb = f2bf(v);
      const int ks = ((k & ~7) ^ ((c & 7) << 3)) | (k & 7);
      bsm[c * 512 + ks] = hb;
      bsm[8192 + c * 512 + ks] = f2bf(v - bf2f(hb));
    }
    __syncthreads();
    {
      const int xorv = (lb & 7) << 3;
      const u16* bsp = bsm + lb * 512;
      const f32x4 b0i = *(const f32x4*)(bh + u * 16 + (lk8 >> 1));
      for (int t = 0; t < SEQ_; ++t) {
        const int row = t * 64 + wv * 16 + lb;           // global XB row
        const u16* Ah = XBhi + (size_t)row * E_ + lk8;
        const u16* Al = XBlo + (size_t)row * E_ + lk8;
        f32x4 a0 = b0i, a1 = {0,0,0,0}, a2 = {0,0,0,0};
#pragma unroll
        for (int kc = 0; kc < 16; ++kc) {
          bf16x8 ah = *(const bf16x8*)(Ah + kc * 32);
          bf16x8 al = *(const bf16x8*)(Al + kc * 32);
          bf16x8 bhf = *(const bf16x8*)(bsp + ((kc * 32 + lk8) ^ xorv));
          bf16x8 blf = *(const bf16x8*)(bsp + 8192 + ((kc * 32 + lk8) ^ xorv));
          a0 = __builtin_amdgcn_mfma_f32_16x16x32_bf16(bhf, ah, a0, 0, 0, 0);
          a1 = __builtin_amdgcn_mfma_f32_16x16x32_bf16(blf, ah, a1, 0, 0, 0);
          a2 = __builtin_amdgcn_mfma_f32_16x16x32_bf16(bhf, al, a2, 0, 0, 0);
        }
        f32x4 acc = a0 + a1 + a2;
        // r9 FIX: row is global (t*64+b) -> XP0 offset is row*H_ only.
        float* p = XP0 + (size_t)row * H_ + u * 16 + (lk8 >> 1);
        st64(p,     pk64(acc[0], acc[1]));
        st64(p + 2, pk64(acc[2], acc[3]));
        asm volatile("s_waitcnt vmcnt(0)" ::: "memory");
        __syncthreads();
        if (tid == 0) {
          unsigned old = __hip_atomic_fetch_add(xpcnt + t, 1u, __ATOMIC_RELAXED,
                                                __HIP_MEMORY_SCOPE_AGENT);
          if (old == 63u)
            __hip_atomic_store(xphw, (unsigned)(t + 1), __ATOMIC_RELAXED,
                               __HIP_MEMORY_SCOPE_AGENT);
        }
      }
    }

    // ---- Phase B: streaming logits (slot s as h1[s] becomes available) ----
    const int xorva = (lb & 7) << 3;
    for (int s = 1; s <= SEQ_; ++s) {
      wait_flags(flags, (unsigned)(s + 2));
      __syncthreads();
      for (int c = tid; c < 8192; c += 256) {            // stage h1 slot s
        const int row = c >> 7, ch = c & 127;
        *(u16x8*)(bsm + row * 1024 + ((ch * 8) ^ ((row & 7) << 3))) =
            *(const u16x8*)(H1hi + (size_t)s * BH_ + (size_t)row * H_ + ch * 8);
      }
      __syncthreads();
#pragma unroll 1
      for (int blk = 0; blk < 2; ++blk) {
        const int nb = u + blk * 64;
        if (nb >= 79) break;
        f32x4 acc[4][2] = {};
#pragma unroll
        for (int kc = 0; kc < 32; ++kc) {
          bf16x8 a[4], b[2];
#pragma unroll
          for (int mt = 0; mt < 4; ++mt)
            a[mt] = *(const bf16x8*)(bsm + (mt * 16 + lb) * 1024 +
                                     ((kc * 32 + lk8) ^ xorva));
#pragma unroll
          for (int nt = 0; nt < 2; ++nt)
            b[nt] = *(const bf16x8*)(WoutT +
                     (size_t)(nb * 128 + wv * 32 + nt * 16 + lb) * 1024 +
                     kc * 32 + lk8);
#pragma unroll
          for (int mt = 0; mt < 4; ++mt)
#pragma unroll
            for (int nt = 0; nt < 2; ++nt)
              acc[mt][nt] = __builtin_amdgcn_mfma_f32_16x16x32_bf16(
                  a[mt], b[nt], acc[mt][nt], 0, 0, 0);
        }
#pragma unroll
        for (int mt = 0; mt < 4; ++mt)
#pragma unroll
          for (int nt = 0; nt < 2; ++nt)
#pragma unroll
            for (int r = 0; r < 4; ++r) {
              const int rowg = (s - 1) * 64 + mt * 16 + (lane >> 4) * 4 + r;
              const int colg = nb * 128 + wv * 32 + nt * 16 + lb;
              if (colg < V_)
                out[(size_t)rowg * V_ + colg] = acc[mt][nt][r] + bout[colg];
            }
      }
    }
  }
}

// --------------------------- launch ----------------------------------------
extern "C" void kernel_launch(void* const* d_in, const int* in_sizes, int n_in,
                              void* d_out, int out_size, void* d_ws, size_t ws_size,
                              hipStream_t stream)
{
  (void)in_sizes; (void)n_in; (void)out_size; (void)ws_size; // ~170 MB ws
  const int*   toks = (const int*)d_in[0];
  const float* hid0 = (const float*)d_in[1];
  const float* emb  = (const float*)d_in[2];
  const float* Wx0  = (const float*)d_in[3];
  const float* Wx1  = (const float*)d_in[4];
  const float* Wh   = (const float*)d_in[5];
  const float* bh   = (const float*)d_in[6];
  const float* Wout = (const float*)d_in[7];
  const float* bout = (const float*)d_in[8];
  float* out = (float*)d_out;

  char* ws = (char*)d_ws;
  size_t off = 0;
  auto alloc = [&](size_t bytes) -> void* {
    void* p = ws + off;
    off += (bytes + 255) & ~(size_t)255;
    return p;
  };
  unsigned* flags = (unsigned*)alloc(192 * 16 * 4);      // 12 KB
  unsigned* xpcnt = (unsigned*)alloc(SEQ_ * 4 + 64);     // + xphw
  unsigned* xphw  = xpcnt + SEQ_;
  u16* XBhi  = (u16*)alloc((size_t)ROWS_ * E_ * 2);
  u16* XBlo  = (u16*)alloc((size_t)ROWS_ * E_ * 2);
  u16* WoutT = (u16*)alloc((size_t)VP_ * H_ * 2);
  float* XP0 = (float*)alloc((size_t)ROWS_ * H_ * 4);
  float* Pbuf= (float*)alloc((size_t)SEQ_ * BH_ * 4);
  u16* H0hi  = (u16*)alloc((size_t)(SEQ_ + 1) * BH_ * 2);
  u16* H0lo  = (u16*)alloc((size_t)(SEQ_ + 1) * BH_ * 2);
  u16* H1hi  = (u16*)alloc((size_t)(SEQ_ + 1) * BH_ * 2);
  u16* H1lo  = (u16*)alloc((size_t)(SEQ_ + 1) * BH_ * 2);

  hipMemsetAsync(flags, 0, 192 * 16 * 4, stream);
  hipMemsetAsync(xpcnt, 0, SEQ_ * 4 + 64, stream);

  transpose_bf16<<<dim3(VP_ / 32, H_ / 32), 256, 0, stream>>>(Wout, WoutT, H_, V_);
  gather_x<<<ROWS_ * E_ / 8 / 256, 256, 0, stream>>>(toks, emb, XBhi, XBlo);
  hid_cast<<<BH_ / 256, 256, 0, stream>>>(hid0, H0hi, H0lo, H1hi, H1lo);

  rnn_mega<<<256, 256, 0, stream>>>(Wh, Wx1, Wx0, WoutT, XBhi, XBlo,
                                    bh, bout, XP0, Pbuf,
                                    H0hi, H0lo, H1hi, H1lo,
                                    out, out + LOGITS_, out + LOGITS_ + BH_,
                                    flags, xpcnt, xphw);
}

// Round 10
// 4213.347 us; speedup vs baseline: 1.0032x; 1.0032x over previous
//
#include <hip/hip_runtime.h>
#include <math.h>

// ---------------------------------------------------------------------------
// Stacked vanilla RNN (2 layers), SEQ=128 B=64 E=512 H=1024 V=10000.
// Persistent 256-WG mega-kernel:
//   WGs 0..191  : r2-proven fused recurrence (roles L0/P/L1, global barrier,
//                 130 stages), weights self-staged from f32.
//   WGs 192..255: XW role. Phase A: incremental XP0 (publishes xphw counter
//                 consumed by L0). Phase B: streaming logits GEMM, gated by a
//                 per-consumer generation broadcast (genpub) published by WG0
//                 after each barrier — NO scanning of the barrier flag array
//                 by non-barrier WGs (r9's contention bug).
// Serial prep: gather_x, hid_cast, W_out transpose only.
// ---------------------------------------------------------------------------

typedef unsigned short u16;
typedef unsigned int u32;
typedef unsigned long long u64;
typedef __bf16 bf16x8 __attribute__((ext_vector_type(8)));
typedef float  f32x4  __attribute__((ext_vector_type(4)));
typedef u32 u32x4 __attribute__((ext_vector_type(4)));
typedef u16 u16x8 __attribute__((ext_vector_type(8)));

#define SEQ_ 128
#define B_   64
#define E_   512
#define H_   1024
#define V_   10000
#define VP_  10112
#define ROWS_ (SEQ_*B_)      // 8192
#define BH_  (B_*H_)         // 65536
#define LOGITS_ 81920000     // SEQ*B*V

__device__ __forceinline__ u16 f2bf(float f) {          // RNE f32 -> bf16
  unsigned u = __builtin_bit_cast(unsigned, f);
  u += 0x7fffu + ((u >> 16) & 1u);
  return (u16)(u >> 16);
}
__device__ __forceinline__ float bf2f(u16 h) {
  unsigned u = ((unsigned)h) << 16;
  return __builtin_bit_cast(float, u);
}
__device__ __forceinline__ void st64(void* p, u64 v) {   // agent write-through
  __hip_atomic_store((u64*)p, v, __ATOMIC_RELAXED, __HIP_MEMORY_SCOPE_AGENT);
}
__device__ __forceinline__ u64 pk64(float a, float b) {
  return (u64)__builtin_bit_cast(unsigned, a) |
         ((u64)__builtin_bit_cast(unsigned, b) << 32);
}
__device__ __forceinline__ float tanh_fast(float x) {
  float e = __expf(2.0f * x);
  return 1.0f - 2.0f * __builtin_amdgcn_rcpf(e + 1.0f);
}

// --------------------------- prep kernels ----------------------------------

// in: f32 [K][N] row-major -> out: bf16 [NP][K] (transposed). For W_out only.
__global__ __launch_bounds__(256)
void transpose_bf16(const float* __restrict__ in, u16* __restrict__ outHi,
                    int K, int N)
{
  __shared__ float tile[32][33];
  const int n0 = blockIdx.x * 32, k0 = blockIdx.y * 32;
  const int x = threadIdx.x & 31;
  const int y = threadIdx.x >> 5;
#pragma unroll
  for (int i = 0; i < 4; ++i) {
    const int r = y * 4 + i;
    const int n = n0 + x;
    tile[r][x] = (n < N) ? in[(size_t)(k0 + r) * N + n] : 0.f;
  }
  __syncthreads();
#pragma unroll
  for (int i = 0; i < 4; ++i) {
    const int r = y * 4 + i;
    outHi[(size_t)(n0 + r) * K + k0 + x] = f2bf(tile[x][r]);
  }
}

__global__ __launch_bounds__(256)
void gather_x(const int* __restrict__ toks, const float* __restrict__ emb,
              u16* __restrict__ XBhi, u16* __restrict__ XBlo)
{
  const int tid = blockIdx.x * 256 + threadIdx.x;
  const int row = tid >> 6;
  const int c8 = (tid & 63) * 8;
  const int tok = toks[row];
  const float* e = emb + (size_t)tok * E_ + c8;
  u16x8 hv, lv;
#pragma unroll
  for (int j = 0; j < 8; ++j) {
    float f = e[j] * 22.627416997969522f;            // sqrt(512)
    u16 hb = f2bf(f);
    hv[j] = hb;
    lv[j] = f2bf(f - bf2f(hb));
  }
  *(u16x8*)(XBhi + (size_t)row * E_ + c8) = hv;
  *(u16x8*)(XBlo + (size_t)row * E_ + c8) = lv;
}

__global__ __launch_bounds__(256)
void hid_cast(const float* __restrict__ h, u16* H0hi, u16* H0lo, u16* H1hi, u16* H1lo)
{
  const int tid = blockIdx.x * 256 + threadIdx.x;
  float v0 = h[tid], v1 = h[BH_ + tid];
  u16 a = f2bf(v0); H0hi[tid] = a; H0lo[tid] = f2bf(v0 - bf2f(a));
  u16 b = f2bf(v1); H1hi[tid] = b; H1lo[tid] = f2bf(v1 - bf2f(b));
}

// --------------------------- barrier (r2-proven) ----------------------------
// 192 arrivals; every recurrence WG's wave0 scans all 192 flags.
__device__ __forceinline__ void gbar(unsigned* flags, unsigned my)
{
  asm volatile("s_waitcnt vmcnt(0)" ::: "memory");
  __syncthreads();
  if (threadIdx.x == 0)
    __hip_atomic_store(flags + blockIdx.x * 16u, my, __ATOMIC_RELAXED,
                       __HIP_MEMORY_SCOPE_AGENT);
  if (threadIdx.x < 64) {
    const int l = threadIdx.x;
    bool ok0 = false, ok1 = false, ok2 = false;
    for (;;) {
      if (!ok0) ok0 = __hip_atomic_load(flags + l * 16,         __ATOMIC_RELAXED, __HIP_MEMORY_SCOPE_AGENT) >= my;
      if (!ok1) ok1 = __hip_atomic_load(flags + (l + 64) * 16,  __ATOMIC_RELAXED, __HIP_MEMORY_SCOPE_AGENT) >= my;
      if (!ok2) ok2 = __hip_atomic_load(flags + (l + 128) * 16, __ATOMIC_RELAXED, __HIP_MEMORY_SCOPE_AGENT) >= my;
      if (__all(ok0 && ok1 && ok2)) break;
      __builtin_amdgcn_s_sleep(2);
    }
  }
  __syncthreads();
}

// --------------------------- recurrence GEMM core ---------------------------
// 96 MFMAs: acc += Ahi*Bhi + Ahi*Blo + Alo*Bhi over K=1024, 3 acc chains.
__device__ __forceinline__ f32x4 gemm96(const u16* __restrict__ Ahi,
                                        const u16* __restrict__ Alo,
                                        const u16* bsp, int xorv, int lk8,
                                        size_t aoff, f32x4 acc0)
{
  f32x4 acc1 = {0.f, 0.f, 0.f, 0.f};
  f32x4 acc2 = {0.f, 0.f, 0.f, 0.f};
#pragma unroll
  for (int kc = 0; kc < 32; ++kc) {
    bf16x8 ah = *(const bf16x8*)(Ahi + aoff + kc * 32);
    bf16x8 al = *(const bf16x8*)(Alo + aoff + kc * 32);
    bf16x8 bh = *(const bf16x8*)(bsp + ((kc * 32 + lk8) ^ xorv));
    bf16x8 bl = *(const bf16x8*)(bsp + 32768 + ((kc * 32 + lk8) ^ xorv));
    acc0 = __builtin_amdgcn_mfma_f32_16x16x32_bf16(bh, ah, acc0, 0, 0, 0);
    acc1 = __builtin_amdgcn_mfma_f32_16x16x32_bf16(bl, ah, acc1, 0, 0, 0);
    acc2 = __builtin_amdgcn_mfma_f32_16x16x32_bf16(bh, al, acc2, 0, 0, 0);
  }
  return acc0 + acc1 + acc2;
}

// --------------------------- mega kernel ------------------------------------
__global__ __launch_bounds__(256, 1)
void rnn_mega(const float* __restrict__ Wh,    // (2,H,H) f32, layer-major
              const float* __restrict__ Wx1f,  // (H,H)  f32
              const float* __restrict__ Wx0f,  // (E,H)  f32
              const u16*   __restrict__ WoutT, // (VP,H) bf16 [n][k]
              const u16*   __restrict__ XBhi, const u16* __restrict__ XBlo,
              const float* __restrict__ bh,    // (2,H)
              const float* __restrict__ bout,  // (V)
              float* __restrict__ XP0, float* __restrict__ Pbuf,
              u16* __restrict__ H0hi, u16* __restrict__ H0lo,
              u16* __restrict__ H1hi, u16* __restrict__ H1lo,
              float* __restrict__ out,
              float* __restrict__ final0, float* __restrict__ final1,
              unsigned* __restrict__ flags, unsigned* __restrict__ xpcnt,
              unsigned* __restrict__ xphw, unsigned* __restrict__ genpub)
{
  __shared__ u16 bsm[2 * 32 * 1024];   // 128 KB, role-dependent layout

  const int wg   = blockIdx.x;
  const int tid  = threadIdx.x;
  const int wv   = tid >> 6, lane = tid & 63;
  const int lb   = lane & 15;
  const int lk8  = (lane >> 4) * 8;

  if (wg < 192) {
    // ===================== recurrence roles (r2 structure) =================
    const int role = wg >> 6;           // 0=L0, 1=P, 2=L1
    const int idx  = wg & 63;
    const int bg   = idx >> 5, cg = idx & 31;

    // self-stage 32-col weight strip (hi+lo) from original f32 [k][n]
    const float* Wsrc = (role == 0) ? Wh : (role == 1) ? Wx1f : (Wh + H_ * H_);
    for (int j = tid; j < 32768; j += 256) {
      const int k = j >> 5, c = j & 31;
      const float v = Wsrc[(size_t)k * H_ + cg * 32 + c];
      const u16 hb = f2bf(v);
      const int ks = ((k & ~7) ^ ((c & 7) << 3)) | (k & 7);
      bsm[c * 1024 + ks] = hb;
      bsm[32768 + c * 1024 + ks] = f2bf(v - bf2f(hb));
    }
    __syncthreads();

    const int wbg = wv >> 1, wcg = wv & 1;
    const int batch = bg * 32 + wbg * 16 + lb;
    const int c0    = cg * 32 + wcg * 16 + (lk8 >> 1);
    const int colL  = wcg * 16 + lb;
    const int xorv  = (colL & 7) << 3;
    const u16* bsp  = bsm + colL * 1024;
    const size_t aoff = (size_t)batch * H_ + lk8;
    const size_t boff = (size_t)batch * H_ + c0;
    const f32x4 binit = *(const f32x4*)(bh + H_ + c0);   // b1 (used by P)

    unsigned xph = 0;                                    // L0: cached high-water
    for (int i = 0; i < 130; ++i) {
      if (role == 0) {
        if (i < 128) {
          const int t = i;
          if (tid < 64) {                                // gate on XP0[t]
            while (xph <= (unsigned)t) {
              xph = __hip_atomic_load(xphw, __ATOMIC_RELAXED, __HIP_MEMORY_SCOPE_AGENT);
              if (xph <= (unsigned)t) __builtin_amdgcn_s_sleep(2);
            }
          }
          __syncthreads();
          f32x4 init = *(const f32x4*)(XP0 + (size_t)t * BH_ + boff);
          f32x4 acc = gemm96(H0hi + (size_t)t * BH_, H0lo + (size_t)t * BH_,
                             bsp, xorv, lk8, aoff, init);
          u64 whi = 0, wlo = 0; float hv[4];
#pragma unroll
          for (int r = 0; r < 4; ++r) {
            float v = tanh_fast(acc[r]);
            u16 hb = f2bf(v);
            whi |= (u64)hb << (16 * r);
            wlo |= (u64)f2bf(v - bf2f(hb)) << (16 * r);
            hv[r] = v;
          }
          st64(H0hi + (size_t)(t + 1) * BH_ + boff, whi);
          st64(H0lo + (size_t)(t + 1) * BH_ + boff, wlo);
          if (t == SEQ_ - 1) {
            st64(final0 + boff,     pk64(hv[0], hv[1]));
            st64(final0 + boff + 2, pk64(hv[2], hv[3]));
          }
        }
      } else if (role == 1) {
        if (i >= 1 && i < 129) {
          f32x4 acc = gemm96(H0hi + (size_t)i * BH_, H0lo + (size_t)i * BH_,
                             bsp, xorv, lk8, aoff, binit);
          float* op = Pbuf + (size_t)(i - 1) * BH_ + boff;
          st64(op,     pk64(acc[0], acc[1]));
          st64(op + 2, pk64(acc[2], acc[3]));
        }
      } else {
        if (i >= 2) {
          const int t = i - 2;
          f32x4 init = *(const f32x4*)(Pbuf + (size_t)t * BH_ + boff);
          f32x4 acc = gemm96(H1hi + (size_t)t * BH_, H1lo + (size_t)t * BH_,
                             bsp, xorv, lk8, aoff, init);
          u64 whi = 0, wlo = 0; float hv[4];
#pragma unroll
          for (int r = 0; r < 4; ++r) {
            float v = tanh_fast(acc[r]);
            u16 hb = f2bf(v);
            whi |= (u64)hb << (16 * r);
            wlo |= (u64)f2bf(v - bf2f(hb)) << (16 * r);
            hv[r] = v;
          }
          st64(H1hi + (size_t)(t + 1) * BH_ + boff, whi);
          st64(H1lo + (size_t)(t + 1) * BH_ + boff, wlo);
          if (t == SEQ_ - 1) {
            st64(final1 + boff,     pk64(hv[0], hv[1]));
            st64(final1 + boff + 2, pk64(hv[2], hv[3]));
          }
        }
      }
      gbar(flags, (unsigned)(i + 1));
      // r10: WG0 broadcasts the completed generation to 64 per-consumer
      // padded words. Payloads are globally drained before flags (producer
      // vmcnt(0) -> flag), and WG0 observed all flags >= i+1 -> transitively
      // safe for phase-B readers.
      if (wg == 0 && tid < 64)
        __hip_atomic_store(genpub + tid * 16, (unsigned)(i + 1),
                           __ATOMIC_RELAXED, __HIP_MEMORY_SCOPE_AGENT);
    }
  } else {
    // ============================ XW role ==================================
    const int u = wg - 192;                              // 0..63

    // ---- Phase A: incremental XP0 (16-col strip, K=512, 3-pass) ----
    for (int j = tid; j < 8192; j += 256) {              // stage Wx0 strip
      const int k = j >> 4, c = j & 15;
      const float v = Wx0f[(size_t)k * H_ + u * 16 + c];
      const u16 hb = f2bf(v);
      const int ks = ((k & ~7) ^ ((c & 7) << 3)) | (k & 7);
      bsm[c * 512 + ks] = hb;
      bsm[8192 + c * 512 + ks] = f2bf(v - bf2f(hb));
    }
    __syncthreads();
    {
      const int xorv = (lb & 7) << 3;
      const u16* bsp = bsm + lb * 512;
      const f32x4 b0i = *(const f32x4*)(bh + u * 16 + (lk8 >> 1));
      for (int t = 0; t < SEQ_; ++t) {
        const int row = t * 64 + wv * 16 + lb;           // global XB row
        const u16* Ah = XBhi + (size_t)row * E_ + lk8;
        const u16* Al = XBlo + (size_t)row * E_ + lk8;
        f32x4 a0 = b0i, a1 = {0,0,0,0}, a2 = {0,0,0,0};
#pragma unroll
        for (int kc = 0; kc < 16; ++kc) {
          bf16x8 ah = *(const bf16x8*)(Ah + kc * 32);
          bf16x8 al = *(const bf16x8*)(Al + kc * 32);
          bf16x8 bhf = *(const bf16x8*)(bsp + ((kc * 32 + lk8) ^ xorv));
          bf16x8 blf = *(const bf16x8*)(bsp + 8192 + ((kc * 32 + lk8) ^ xorv));
          a0 = __builtin_amdgcn_mfma_f32_16x16x32_bf16(bhf, ah, a0, 0, 0, 0);
          a1 = __builtin_amdgcn_mfma_f32_16x16x32_bf16(blf, ah, a1, 0, 0, 0);
          a2 = __builtin_amdgcn_mfma_f32_16x16x32_bf16(bhf, al, a2, 0, 0, 0);
        }
        f32x4 acc = a0 + a1 + a2;
        float* p = XP0 + (size_t)row * H_ + u * 16 + (lk8 >> 1);
        st64(p,     pk64(acc[0], acc[1]));
        st64(p + 2, pk64(acc[2], acc[3]));
        asm volatile("s_waitcnt vmcnt(0)" ::: "memory");
        __syncthreads();
        if (tid == 0) {
          unsigned old = __hip_atomic_fetch_add(xpcnt + t, 1u, __ATOMIC_RELAXED,
                                                __HIP_MEMORY_SCOPE_AGENT);
          if (old == 63u)
            __hip_atomic_store(xphw, (unsigned)(t + 1), __ATOMIC_RELAXED,
                               __HIP_MEMORY_SCOPE_AGENT);
        }
      }
    }

    // ---- Phase B: streaming logits (slot s as h1[s] becomes available) ----
    // r10: gate on private genpub[u] with register caching (near-zero polls
    // when behind; sleep(16) backoff when caught up).
    const int xorva = (lb & 7) << 3;
    unsigned geng = 0;
    for (int s = 1; s <= SEQ_; ++s) {
      if (tid < 64) {
        while (geng < (unsigned)(s + 2)) {
          geng = __hip_atomic_load(genpub + u * 16, __ATOMIC_RELAXED,
                                   __HIP_MEMORY_SCOPE_AGENT);
          if (geng < (unsigned)(s + 2)) __builtin_amdgcn_s_sleep(16);
        }
      }
      __syncthreads();
      for (int c = tid; c < 8192; c += 256) {            // stage h1 slot s
        const int row = c >> 7, ch = c & 127;
        *(u16x8*)(bsm + row * 1024 + ((ch * 8) ^ ((row & 7) << 3))) =
            *(const u16x8*)(H1hi + (size_t)s * BH_ + (size_t)row * H_ + ch * 8);
      }
      __syncthreads();
#pragma unroll 1
      for (int blk = 0; blk < 2; ++blk) {
        const int nb = u + blk * 64;
        if (nb >= 79) break;
        f32x4 acc[4][2] = {};
#pragma unroll
        for (int kc = 0; kc < 32; ++kc) {
          bf16x8 a[4], b[2];
#pragma unroll
          for (int mt = 0; mt < 4; ++mt)
            a[mt] = *(const bf16x8*)(bsm + (mt * 16 + lb) * 1024 +
                                     ((kc * 32 + lk8) ^ xorva));
#pragma unroll
          for (int nt = 0; nt < 2; ++nt)
            b[nt] = *(const bf16x8*)(WoutT +
                     (size_t)(nb * 128 + wv * 32 + nt * 16 + lb) * 1024 +
                     kc * 32 + lk8);
#pragma unroll
          for (int mt = 0; mt < 4; ++mt)
#pragma unroll
            for (int nt = 0; nt < 2; ++nt)
              acc[mt][nt] = __builtin_amdgcn_mfma_f32_16x16x32_bf16(
                  a[mt], b[nt], acc[mt][nt], 0, 0, 0);
        }
#pragma unroll
        for (int mt = 0; mt < 4; ++mt)
#pragma unroll
          for (int nt = 0; nt < 2; ++nt)
#pragma unroll
            for (int r = 0; r < 4; ++r) {
              const int rowg = (s - 1) * 64 + mt * 16 + (lane >> 4) * 4 + r;
              const int colg = nb * 128 + wv * 32 + nt * 16 + lb;
              if (colg < V_)
                out[(size_t)rowg * V_ + colg] = acc[mt][nt][r] + bout[colg];
            }
      }
    }
  }
}

// --------------------------- launch ----------------------------------------
extern "C" void kernel_launch(void* const* d_in, const int* in_sizes, int n_in,
                              void* d_out, int out_size, void* d_ws, size_t ws_size,
                              hipStream_t stream)
{
  (void)in_sizes; (void)n_in; (void)out_size; (void)ws_size; // ~170 MB ws
  const int*   toks = (const int*)d_in[0];
  const float* hid0 = (const float*)d_in[1];
  const float* emb  = (const float*)d_in[2];
  const float* Wx0  = (const float*)d_in[3];
  const float* Wx1  = (const float*)d_in[4];
  const float* Wh   = (const float*)d_in[5];
  const float* bh   = (const float*)d_in[6];
  const float* Wout = (const float*)d_in[7];
  const float* bout = (const float*)d_in[8];
  float* out = (float*)d_out;

  char* ws = (char*)d_ws;
  size_t off = 0;
  auto alloc = [&](size_t bytes) -> void* {
    void* p = ws + off;
    off += (bytes + 255) & ~(size_t)255;
    return p;
  };
  unsigned* flags  = (unsigned*)alloc(192 * 16 * 4);     // 12 KB
  unsigned* xpcnt  = (unsigned*)alloc(SEQ_ * 4 + 64);    // + xphw
  unsigned* xphw   = xpcnt + SEQ_;
  unsigned* genpub = (unsigned*)alloc(64 * 16 * 4);      // 4 KB, padded words
  u16* XBhi  = (u16*)alloc((size_t)ROWS_ * E_ * 2);
  u16* XBlo  = (u16*)alloc((size_t)ROWS_ * E_ * 2);
  u16* WoutT = (u16*)alloc((size_t)VP_ * H_ * 2);
  float* XP0 = (float*)alloc((size_t)ROWS_ * H_ * 4);
  float* Pbuf= (float*)alloc((size_t)SEQ_ * BH_ * 4);
  u16* H0hi  = (u16*)alloc((size_t)(SEQ_ + 1) * BH_ * 2);
  u16* H0lo  = (u16*)alloc((size_t)(SEQ_ + 1) * BH_ * 2);
  u16* H1hi  = (u16*)alloc((size_t)(SEQ_ + 1) * BH_ * 2);
  u16* H1lo  = (u16*)alloc((size_t)(SEQ_ + 1) * BH_ * 2);

  hipMemsetAsync(flags, 0, 192 * 16 * 4, stream);
  hipMemsetAsync(xpcnt, 0, SEQ_ * 4 + 64, stream);
  hipMemsetAsync(genpub, 0, 64 * 16 * 4, stream);

  transpose_bf16<<<dim3(VP_ / 32, H_ / 32), 256, 0, stream>>>(Wout, WoutT, H_, V_);
  gather_x<<<ROWS_ * E_ / 8 / 256, 256, 0, stream>>>(toks, emb, XBhi, XBlo);
  hid_cast<<<BH_ / 256, 256, 0, stream>>>(hid0, H0hi, H0lo, H1hi, H1lo);

  rnn_mega<<<256, 256, 0, stream>>>(Wh, Wx1, Wx0, WoutT, XBhi, XBlo,
                                    bh, bout, XP0, Pbuf,
                                    H0hi, H0lo, H1hi, H1lo,
                                    out, out + LOGITS_, out + LOGITS_ + BH_,
                                    flags, xpcnt, xphw, genpub);
}